// Round 7
// baseline (597.146 us; speedup 1.0000x reference)
//
#include <hip/hip_runtime.h>

#define N_NODES 50000
#define N_EDGES 800000
#define BN_EPS 1e-5f
#define SCAN_BLOCKS 196   // ceil(50000/256)
#define K_BUCK 196        // dst >> 8 buckets (256 nodes each)
#define PART_B 256        // partition blocks
#define CHUNK 3125        // N_EDGES / PART_B

typedef __attribute__((ext_vector_type(8))) short bshort8;
typedef __attribute__((ext_vector_type(4))) float f32x4;

__device__ inline float bf2f(unsigned int u16) {
    return __uint_as_float(u16 << 16);
}
__device__ inline unsigned short f2bf(float f) {
    unsigned int u = __float_as_uint(f);
    u = (u + 0x7FFFu + ((u >> 16) & 1u)) >> 16;
    return (unsigned short)u;
}

// ---------------- CSR build ----------------

__global__ void hist_kernel(const int* __restrict__ dst, int* __restrict__ deg, int e) {
    int i = blockIdx.x * blockDim.x + threadIdx.x;
    int stride = gridDim.x * blockDim.x;
    for (; i < e; i += stride) atomicAdd(&deg[dst[i]], 1);
}

__device__ inline int block_exscan256(int v, int tid, int* total) {
    int lane = tid & 63;
    int wave = tid >> 6;
    int incl = v;
#pragma unroll
    for (int off = 1; off < 64; off <<= 1) {
        int t = __shfl_up(incl, off, 64);
        if (lane >= off) incl += t;
    }
    __shared__ int wsum[4];
    if (lane == 63) wsum[wave] = incl;
    __syncthreads();
    int w0 = wsum[0], w1 = wsum[1], w2 = wsum[2], w3 = wsum[3];
    __syncthreads();
    int wofs = (wave > 0 ? w0 : 0) + (wave > 1 ? w1 : 0) + (wave > 2 ? w2 : 0);
    *total = w0 + w1 + w2 + w3;
    return wofs + incl - v;
}

__global__ __launch_bounds__(256) void scan_reduce_kernel(const int* __restrict__ in,
                                                          int* __restrict__ bsum, int n) {
    int tid = threadIdx.x;
    int i = blockIdx.x * 256 + tid;
    int v = (i < n) ? in[i] : 0;
    int lane = tid & 63;
    int wave = tid >> 6;
#pragma unroll
    for (int off = 32; off > 0; off >>= 1) v += __shfl_down(v, off, 64);
    __shared__ int wsum[4];
    if (lane == 0) wsum[wave] = v;
    __syncthreads();
    if (tid == 0) bsum[blockIdx.x] = wsum[0] + wsum[1] + wsum[2] + wsum[3];
}

__global__ __launch_bounds__(256) void scan_bsum_kernel(int* __restrict__ bsum, int B,
                                                        int* __restrict__ totout) {
    int tid = threadIdx.x;
    int v = (tid < B) ? bsum[tid] : 0;
    int total;
    int excl = block_exscan256(v, tid, &total);
    if (tid < B) bsum[tid] = excl;
    if (tid == 0) *totout = total;
}

// out[i] = bsum[blk] + exclusive_prefix(in[i]); in-place safe (in==out ok)
__global__ __launch_bounds__(256) void scan_apply_kernel(const int* __restrict__ in,
                                                         const int* __restrict__ bsum,
                                                         int* __restrict__ out, int n) {
    int tid = threadIdx.x;
    int i = blockIdx.x * 256 + tid;
    int v = (i < n) ? in[i] : 0;
    int total;
    int excl = block_exscan256(v, tid, &total);
    if (i < n) out[i] = bsum[blockIdx.x] + excl;
}

// ---- bucketed scatter ----

__global__ __launch_bounds__(256) void bucket_count_kernel(const int* __restrict__ dst,
                                                           int* __restrict__ cnt) {
    __shared__ int lcnt[K_BUCK];
    int tid = threadIdx.x;
    for (int i = tid; i < K_BUCK; i += 256) lcnt[i] = 0;
    __syncthreads();
    int start = blockIdx.x * CHUNK;
    for (int it = tid; it < CHUNK; it += 256)
        atomicAdd(&lcnt[dst[start + it] >> 8], 1);
    __syncthreads();
    for (int i = tid; i < K_BUCK; i += 256) cnt[i * PART_B + blockIdx.x] = lcnt[i];
}

__global__ __launch_bounds__(256) void partition_kernel(const int* __restrict__ src,
                                                        const int* __restrict__ dst,
                                                        const int* __restrict__ base,
                                                        uint2* __restrict__ P) {
    __shared__ int lofs[K_BUCK];
    int tid = threadIdx.x;
    for (int i = tid; i < K_BUCK; i += 256) lofs[i] = base[i * PART_B + blockIdx.x];
    __syncthreads();
    int start = blockIdx.x * CHUNK;
    for (int it = tid; it < CHUNK; it += 256) {
        int e = start + it;
        int d = dst[e], s = src[e];
        int p = atomicAdd(&lofs[d >> 8], 1);
        P[p] = make_uint2((unsigned)d, (unsigned)s);
    }
}

__global__ __launch_bounds__(256) void fine_scatter_kernel(const uint2* __restrict__ P,
                                                           const int* __restrict__ base,
                                                           const int* __restrict__ rowptr,
                                                           int* __restrict__ col) {
    __shared__ int wloc[256];
    int b = blockIdx.x;
    int tid = threadIdx.x;
    int nbase = b << 8;
    int nn = min(256, N_NODES - nbase);
    if (tid < nn) wloc[tid] = rowptr[nbase + tid];
    __syncthreads();
    int start = base[b * PART_B];
    int end = (b + 1 < K_BUCK) ? base[(b + 1) * PART_B] : N_EDGES;
    for (int e = start + tid; e < end; e += 256) {
        uint2 pr = P[e];
        int rank = atomicAdd(&wloc[pr.x - nbase], 1);
        col[rank] = (int)pr.y;
    }
}

// ---------------- conversions ----------------

struct WT8 {
    const float* src[8];
    unsigned short* dst[8];
    int K[8];
    int N[8];
};

__global__ __launch_bounds__(256) void wtconv_kernel(WT8 p) {
    int wi = blockIdx.y;
    int K = p.K[wi], N = p.N[wi];
    int idx = blockIdx.x * 256 + threadIdx.x;
    if (idx >= K * N) return;
    int logn = 31 - __clz(N);
    int n = idx & (N - 1);
    int k = idx >> logn;
    p.dst[wi][(size_t)n * K + k] = f2bf(p.src[wi][idx]);
}

// ---------------- aggregation (bf16) ----------------

__device__ inline void acc8(uint4 v, float* a) {
    a[0] += bf2f(v.x & 0xFFFFu); a[1] += __uint_as_float(v.x & 0xFFFF0000u);
    a[2] += bf2f(v.y & 0xFFFFu); a[3] += __uint_as_float(v.y & 0xFFFF0000u);
    a[4] += bf2f(v.z & 0xFFFFu); a[5] += __uint_as_float(v.z & 0xFFFF0000u);
    a[6] += bf2f(v.w & 0xFFFFu); a[7] += __uint_as_float(v.w & 0xFFFF0000u);
}

template <int LPN, bool RELU>
__global__ __launch_bounds__(256) void aggregate_bf16_kernel(
    const unsigned short* __restrict__ h, const int* __restrict__ rowptr,
    const int* __restrict__ col, const float* __restrict__ bias,
    unsigned short* __restrict__ z, int n) {
    const int gpb = 256 / LPN;
    int gid = threadIdx.x / LPN;
    int l = threadIdx.x % LPN;
    int node = blockIdx.x * gpb + gid;
    if (node >= n) return;
    const uint4* hv = (const uint4*)h;
    float a[8] = {};
    acc8(hv[(size_t)node * LPN + l], a);  // self
    int s = rowptr[node], epos = rowptr[node + 1];
    for (int e = s; e < epos; ++e) {
        int j = col[e];
        acc8(hv[(size_t)j * LPN + l], a);
    }
    if (RELU) {
        float4 b0 = *(const float4*)(bias + l * 8);
        float4 b1 = *(const float4*)(bias + l * 8 + 4);
        a[0] = fmaxf(a[0] + b0.x, 0.f); a[1] = fmaxf(a[1] + b0.y, 0.f);
        a[2] = fmaxf(a[2] + b0.z, 0.f); a[3] = fmaxf(a[3] + b0.w, 0.f);
        a[4] = fmaxf(a[4] + b1.x, 0.f); a[5] = fmaxf(a[5] + b1.y, 0.f);
        a[6] = fmaxf(a[6] + b1.z, 0.f); a[7] = fmaxf(a[7] + b1.w, 0.f);
    }
    uint4 o;
    o.x = (unsigned int)f2bf(a[0]) | ((unsigned int)f2bf(a[1]) << 16);
    o.y = (unsigned int)f2bf(a[2]) | ((unsigned int)f2bf(a[3]) << 16);
    o.z = (unsigned int)f2bf(a[4]) | ((unsigned int)f2bf(a[5]) << 16);
    o.w = (unsigned int)f2bf(a[6]) | ((unsigned int)f2bf(a[7]) << 16);
    ((uint4*)z)[(size_t)node * LPN + l] = o;
}

// ---------------- bf16 MFMA GEMM v3 (BM=64, BN=64: 4x grid vs v2) ----------------
// C = epilogue(A @ Wt^T). A: M x K (bf16, or fp32 if F32A). Wt: Nn x K bf16.
// 256 thr = 4 waves; wave (wv>>1, wv&1) owns a 32x32 quadrant (2x2 MFMA tiles).
// Pipelined global->reg prefetch; A/B in LDS; epilogue via LDS, 16B stores.
// mode 0: relu(acc+b); 1: relu((acc+b-mu)*g*rsqrt(var+eps)+be); 2: raw acc

template <bool F32A>
__global__ __launch_bounds__(256) void mfma_gemm3_kernel(
    const void* __restrict__ Ain, const unsigned short* __restrict__ Wt,
    const float* __restrict__ bias, unsigned short* __restrict__ C,
    int M, int K, int Nn, int mode,
    const float* __restrict__ g, const float* __restrict__ be,
    const float* __restrict__ mu, const float* __restrict__ var) {
    constexpr int BM = 64, BK = 64, BN = 64;
    constexpr int LDA = BK + 8;   // 72 shorts
    constexpr int LDB = BK + 8;
    constexpr int LDE = BN + 8;
    __shared__ __align__(16) unsigned short smem[BM * LDA + BN * LDB];
    unsigned short* As = smem;
    unsigned short* Bs = smem + BM * LDA;
    unsigned short* Ep = smem;  // epilogue reuse (64*72 fits)

    const int tid = threadIdx.x;
    const int wv = tid >> 6;
    const int ln = tid & 63;
    const int l15 = ln & 15;
    const int quad = ln >> 4;
    const int wr = (wv >> 1) * 32;  // wave row offset in tile
    const int wc = (wv & 1) * 32;   // wave col offset in tile
    const int row0 = blockIdx.x * BM;
    const int col0 = blockIdx.y * BN;

    const unsigned short* A16 = (const unsigned short*)Ain;
    const float* A32 = (const float*)Ain;

    uint4 Ar[2], Br[2];

    auto loadA = [&](int k0) {
#pragma unroll
        for (int u = 0; u < 2; ++u) {
            int idx2 = tid + 256 * u;
            int r = idx2 >> 3, cg = (idx2 & 7) * 8;
            int gr = row0 + r;
            if (gr >= M) gr = M - 1;  // clamp; OOB rows never stored
            if (F32A) {
                float4 f0 = *(const float4*)(A32 + (size_t)gr * K + k0 + cg);
                float4 f1 = *(const float4*)(A32 + (size_t)gr * K + k0 + cg + 4);
                uint4 o;
                o.x = (unsigned)f2bf(f0.x) | ((unsigned)f2bf(f0.y) << 16);
                o.y = (unsigned)f2bf(f0.z) | ((unsigned)f2bf(f0.w) << 16);
                o.z = (unsigned)f2bf(f1.x) | ((unsigned)f2bf(f1.y) << 16);
                o.w = (unsigned)f2bf(f1.z) | ((unsigned)f2bf(f1.w) << 16);
                Ar[u] = o;
            } else {
                Ar[u] = *(const uint4*)(A16 + (size_t)gr * K + k0 + cg);
            }
        }
    };
    auto loadB = [&](int k0) {
#pragma unroll
        for (int u = 0; u < 2; ++u) {
            int idx2 = tid + 256 * u;
            int r = idx2 >> 3, cg = (idx2 & 7) * 8;
            Br[u] = *(const uint4*)(Wt + (size_t)(col0 + r) * K + k0 + cg);
        }
    };
    auto stage = [&]() {
#pragma unroll
        for (int u = 0; u < 2; ++u) {
            int idx2 = tid + 256 * u;
            int r = idx2 >> 3, cg = (idx2 & 7) * 8;
            *(uint4*)(&As[r * LDA + cg]) = Ar[u];
        }
#pragma unroll
        for (int u = 0; u < 2; ++u) {
            int idx2 = tid + 256 * u;
            int r = idx2 >> 3, cg = (idx2 & 7) * 8;
            *(uint4*)(&Bs[r * LDB + cg]) = Br[u];
        }
    };

    f32x4 acc[2][2] = {};
    const int KT = K >> 6;
    loadA(0);
    loadB(0);
    for (int kt = 0; kt < KT; ++kt) {
        if (kt > 0) __syncthreads();
        stage();
        __syncthreads();
        if (kt + 1 < KT) {
            loadA((kt + 1) * 64);
            loadB((kt + 1) * 64);
        }
#pragma unroll
        for (int kh = 0; kh < 2; ++kh) {
            bshort8 af[2], bf[2];
#pragma unroll
            for (int mt = 0; mt < 2; ++mt)
                af[mt] = *(const bshort8*)(&As[(wr + mt * 16 + l15) * LDA + kh * 32 + quad * 8]);
#pragma unroll
            for (int nt = 0; nt < 2; ++nt)
                bf[nt] = *(const bshort8*)(&Bs[(wc + nt * 16 + l15) * LDB + kh * 32 + quad * 8]);
#pragma unroll
            for (int mt = 0; mt < 2; ++mt)
#pragma unroll
                for (int nt = 0; nt < 2; ++nt)
                    acc[mt][nt] = __builtin_amdgcn_mfma_f32_16x16x32_bf16(af[mt], bf[nt], acc[mt][nt], 0, 0, 0);
        }
    }

    // epilogue: scale/shift/relu -> LDS -> coalesced 16B stores
    __syncthreads();
#pragma unroll
    for (int nt = 0; nt < 2; ++nt) {
        int c = col0 + wc + nt * 16 + l15;
        float s = 1.f, sh = 0.f;
        if (mode == 0) {
            sh = bias[c];
        } else if (mode == 1) {
            float t = g[c] * rsqrtf(var[c] + BN_EPS);
            s = t;
            sh = be[c] - mu[c] * t + bias[c] * t;
        }
#pragma unroll
        for (int mt = 0; mt < 2; ++mt) {
            int rl = wr + mt * 16 + quad * 4;
#pragma unroll
            for (int r = 0; r < 4; ++r) {
                float v = acc[mt][nt][r] * s + sh;
                if (mode != 2) v = fmaxf(v, 0.f);
                Ep[(rl + r) * LDE + wc + nt * 16 + l15] = f2bf(v);
            }
        }
    }
    __syncthreads();
    constexpr int CGR = BN / 8;          // 8 uint4 per row
    constexpr int NU = BM * CGR / 256;   // 2 per thread
#pragma unroll
    for (int u = 0; u < NU; ++u) {
        int idx2 = tid + 256 * u;
        int r = idx2 / CGR, cg = (idx2 % CGR) * 8;
        int grow = row0 + r;
        if (grow < M)
            *(uint4*)(C + (size_t)grow * Nn + col0 + cg) = *(const uint4*)(&Ep[r * LDE + cg]);
    }
}

// ---------------- classifier ----------------

__global__ __launch_bounds__(256) void classifier_kernel(
    const unsigned short* __restrict__ h, const float* __restrict__ wc,
    const float* __restrict__ bc, float* __restrict__ out, int n) {
    int wave = threadIdx.x >> 6;
    int lane = threadIdx.x & 63;
    int row = blockIdx.x * 4 + wave;
    if (row >= n) return;
    float v = bf2f(h[(size_t)row * 64 + lane]);
    float s0 = v * wc[lane * 2 + 0];
    float s1 = v * wc[lane * 2 + 1];
#pragma unroll
    for (int off = 32; off > 0; off >>= 1) {
        s0 += __shfl_down(s0, off, 64);
        s1 += __shfl_down(s1, off, 64);
    }
    if (lane == 0) {
        out[(size_t)row * 2 + 0] = s0 + bc[0];
        out[(size_t)row * 2 + 1] = s1 + bc[1];
    }
}

// ---------------- launch ----------------

extern "C" void kernel_launch(void* const* d_in, const int* in_sizes, int n_in,
                              void* d_out, int out_size, void* d_ws, size_t ws_size,
                              hipStream_t stream) {
    const float* x = (const float*)d_in[0];
    const int* ei = (const int*)d_in[1];
    const int* src = ei;
    const int* dst = ei + N_EDGES;
    const float* w[4][2];
    const float* b[4][2];
    const float* bng[4];
    const float* bnb[4];
    const float* bnm[4];
    const float* bnv[4];
    int idx = 2;
    for (int i = 0; i < 4; ++i) {
        w[i][0] = (const float*)d_in[idx++];
        b[i][0] = (const float*)d_in[idx++];
        w[i][1] = (const float*)d_in[idx++];
        b[i][1] = (const float*)d_in[idx++];
        bng[i] = (const float*)d_in[idx++];
        bnb[i] = (const float*)d_in[idx++];
        bnm[i] = (const float*)d_in[idx++];
        bnv[i] = (const float*)d_in[idx++];
    }
    const float* wc = (const float*)d_in[idx++];
    const float* bc = (const float*)d_in[idx++];
    float* out = (float*)d_out;

    char* ws = (char*)d_ws;
    size_t off = 0;
    auto alloc = [&](size_t bytes) {
        char* p = ws + off;
        off = (off + bytes + 255) & ~(size_t)255;
        return p;
    };
    int* deg = (int*)alloc((size_t)N_NODES * 4);
    int* rowptr = (int*)alloc((size_t)(N_NODES + 1) * 4);
    int* bsum = (int*)alloc((size_t)SCAN_BLOCKS * 4);
    int* cnt = (int*)alloc((size_t)K_BUCK * PART_B * 4);
    int* bsum2 = (int*)alloc((size_t)K_BUCK * 4);
    int* scratch = (int*)alloc(256);
    int* col = (int*)alloc((size_t)N_EDGES * 4);
    uint2* P = (uint2*)alloc((size_t)N_EDGES * 8);
    unsigned short* bufA = (unsigned short*)alloc((size_t)N_NODES * 256 * 2);
    unsigned short* bufB = (unsigned short*)alloc((size_t)N_NODES * 256 * 2);
    unsigned short* bufC = (unsigned short*)alloc((size_t)N_NODES * 256 * 2);
    const int dims_in[4] = {256, 128, 256, 128};
    const int dims_h[4] = {128, 256, 128, 64};
    unsigned short* wt[4][2];
    for (int L = 0; L < 4; ++L) {
        wt[L][0] = (unsigned short*)alloc((size_t)dims_in[L] * dims_h[L] * 2);
        wt[L][1] = (unsigned short*)alloc((size_t)dims_h[L] * dims_h[L] * 2);
    }
    (void)ws_size;

    // weight transpose-convert
    WT8 p;
    for (int L = 0; L < 4; ++L) {
        p.src[L * 2] = w[L][0];     p.dst[L * 2] = wt[L][0];
        p.K[L * 2] = dims_in[L];    p.N[L * 2] = dims_h[L];
        p.src[L * 2 + 1] = w[L][1]; p.dst[L * 2 + 1] = wt[L][1];
        p.K[L * 2 + 1] = dims_h[L]; p.N[L * 2 + 1] = dims_h[L];
    }
    wtconv_kernel<<<dim3(256, 8), 256, 0, stream>>>(p);

    // ---- CSR build ----
    hipMemsetAsync(deg, 0, (size_t)N_NODES * 4, stream);
    hist_kernel<<<3125, 256, 0, stream>>>(dst, deg, N_EDGES);
    scan_reduce_kernel<<<SCAN_BLOCKS, 256, 0, stream>>>(deg, bsum, N_NODES);
    scan_bsum_kernel<<<1, 256, 0, stream>>>(bsum, SCAN_BLOCKS, rowptr + N_NODES);
    scan_apply_kernel<<<SCAN_BLOCKS, 256, 0, stream>>>(deg, bsum, rowptr, N_NODES);
    bucket_count_kernel<<<PART_B, 256, 0, stream>>>(dst, cnt);
    scan_reduce_kernel<<<K_BUCK, 256, 0, stream>>>(cnt, bsum2, K_BUCK * PART_B);
    scan_bsum_kernel<<<1, 256, 0, stream>>>(bsum2, K_BUCK, scratch);
    scan_apply_kernel<<<K_BUCK, 256, 0, stream>>>(cnt, bsum2, cnt, K_BUCK * PART_B);
    partition_kernel<<<PART_B, 256, 0, stream>>>(src, dst, cnt, P);
    fine_scatter_kernel<<<K_BUCK, 256, 0, stream>>>(P, cnt, rowptr, col);

    const int gx = (N_NODES + 63) / 64;  // 782
    const int M = N_NODES;

    // ---- Layer 1 (commuted: GEMM1 256->128 reads fp32 x, agg@128+bias+relu, GEMM2) ----
    mfma_gemm3_kernel<true><<<dim3(gx, 2), 256, 0, stream>>>(
        x, wt[0][0], nullptr, bufA, M, 256, 128, 2, nullptr, nullptr, nullptr, nullptr);
    aggregate_bf16_kernel<16, true><<<(N_NODES + 15) / 16, 256, 0, stream>>>(
        bufA, rowptr, col, b[0][0], bufB, N_NODES);
    mfma_gemm3_kernel<false><<<dim3(gx, 2), 256, 0, stream>>>(
        bufB, wt[0][1], b[0][1], bufC, M, 128, 128, 1, bng[0], bnb[0], bnm[0], bnv[0]);

    // ---- Layer 2 (agg-first: agg@128, GEMM1 128->256 relu, GEMM2 256->256 BN) ----
    aggregate_bf16_kernel<16, false><<<(N_NODES + 15) / 16, 256, 0, stream>>>(
        bufC, rowptr, col, nullptr, bufA, N_NODES);
    mfma_gemm3_kernel<false><<<dim3(gx, 4), 256, 0, stream>>>(
        bufA, wt[1][0], b[1][0], bufB, M, 128, 256, 0, nullptr, nullptr, nullptr, nullptr);
    mfma_gemm3_kernel<false><<<dim3(gx, 4), 256, 0, stream>>>(
        bufB, wt[1][1], b[1][1], bufC, M, 256, 256, 1, bng[1], bnb[1], bnm[1], bnv[1]);

    // ---- Layer 3 (commuted: GEMM1 256->128, agg@128+bias+relu, GEMM2) ----
    mfma_gemm3_kernel<false><<<dim3(gx, 2), 256, 0, stream>>>(
        bufC, wt[2][0], nullptr, bufA, M, 256, 128, 2, nullptr, nullptr, nullptr, nullptr);
    aggregate_bf16_kernel<16, true><<<(N_NODES + 15) / 16, 256, 0, stream>>>(
        bufA, rowptr, col, b[2][0], bufB, N_NODES);
    mfma_gemm3_kernel<false><<<dim3(gx, 2), 256, 0, stream>>>(
        bufB, wt[2][1], b[2][1], bufC, M, 128, 128, 1, bng[2], bnb[2], bnm[2], bnv[2]);

    // ---- Layer 4 (commuted: GEMM1 128->64, agg@64+bias+relu, GEMM2 64->64 BN) ----
    mfma_gemm3_kernel<false><<<dim3(gx, 1), 256, 0, stream>>>(
        bufC, wt[3][0], nullptr, bufA, M, 128, 64, 2, nullptr, nullptr, nullptr, nullptr);
    aggregate_bf16_kernel<8, true><<<(N_NODES + 31) / 32, 256, 0, stream>>>(
        bufA, rowptr, col, b[3][0], bufB, N_NODES);
    mfma_gemm3_kernel<false><<<dim3(gx, 1), 256, 0, stream>>>(
        bufB, wt[3][1], b[3][1], bufC, M, 64, 64, 1, bng[3], bnb[3], bnm[3], bnv[3]);

    classifier_kernel<<<(N_NODES + 3) / 4, 256, 0, stream>>>(bufC, wc, bc, out, N_NODES);
}

// Round 8
// 529.721 us; speedup vs baseline: 1.1273x; 1.1273x over previous
//
#include <hip/hip_runtime.h>

#define N_NODES 50000
#define N_EDGES 800000
#define BN_EPS 1e-5f
#define K_BUCK 196        // dst >> 8 buckets (256 nodes each)
#define PART_B 256        // partition blocks
#define CHUNK 3125        // N_EDGES / PART_B

typedef __attribute__((ext_vector_type(8))) short bshort8;
typedef __attribute__((ext_vector_type(4))) float f32x4;

__device__ inline float bf2f(unsigned int u16) {
    return __uint_as_float(u16 << 16);
}
__device__ inline unsigned short f2bf(float f) {
    unsigned int u = __float_as_uint(f);
    u = (u + 0x7FFFu + ((u >> 16) & 1u)) >> 16;
    return (unsigned short)u;
}

// ---------------- scan helpers ----------------

__device__ inline int block_exscan256(int v, int tid, int* total) {
    int lane = tid & 63;
    int wave = tid >> 6;
    int incl = v;
#pragma unroll
    for (int off = 1; off < 64; off <<= 1) {
        int t = __shfl_up(incl, off, 64);
        if (lane >= off) incl += t;
    }
    __shared__ int wsum[4];
    if (lane == 63) wsum[wave] = incl;
    __syncthreads();
    int w0 = wsum[0], w1 = wsum[1], w2 = wsum[2], w3 = wsum[3];
    __syncthreads();
    int wofs = (wave > 0 ? w0 : 0) + (wave > 1 ? w1 : 0) + (wave > 2 ? w2 : 0);
    *total = w0 + w1 + w2 + w3;
    return wofs + incl - v;
}

__global__ __launch_bounds__(256) void scan_reduce_kernel(const int* __restrict__ in,
                                                          int* __restrict__ bsum, int n) {
    int tid = threadIdx.x;
    int i = blockIdx.x * 256 + tid;
    int v = (i < n) ? in[i] : 0;
    int lane = tid & 63;
    int wave = tid >> 6;
#pragma unroll
    for (int off = 32; off > 0; off >>= 1) v += __shfl_down(v, off, 64);
    __shared__ int wsum[4];
    if (lane == 0) wsum[wave] = v;
    __syncthreads();
    if (tid == 0) bsum[blockIdx.x] = wsum[0] + wsum[1] + wsum[2] + wsum[3];
}

__global__ __launch_bounds__(256) void scan_bsum_kernel(int* __restrict__ bsum, int B) {
    int tid = threadIdx.x;
    int v = (tid < B) ? bsum[tid] : 0;
    int total;
    int excl = block_exscan256(v, tid, &total);
    if (tid < B) bsum[tid] = excl;
}

__global__ __launch_bounds__(256) void scan_apply_kernel(const int* __restrict__ in,
                                                         const int* __restrict__ bsum,
                                                         int* __restrict__ out, int n) {
    int tid = threadIdx.x;
    int i = blockIdx.x * 256 + tid;
    int v = (i < n) ? in[i] : 0;
    int total;
    int excl = block_exscan256(v, tid, &total);
    if (i < n) out[i] = bsum[blockIdx.x] + excl;
}

// ---- bucketed CSR build ----
// bucket histogram + per-node degree histogram in one pass
__global__ __launch_bounds__(256) void bucket_count_kernel(const int* __restrict__ dst,
                                                           int* __restrict__ deg,
                                                           int* __restrict__ cnt) {
    __shared__ int lcnt[K_BUCK];
    int tid = threadIdx.x;
    for (int i = tid; i < K_BUCK; i += 256) lcnt[i] = 0;
    __syncthreads();
    int start = blockIdx.x * CHUNK;
    for (int it = tid; it < CHUNK; it += 256) {
        int d = dst[start + it];
        atomicAdd(&lcnt[d >> 8], 1);
        atomicAdd(&deg[d], 1);
    }
    __syncthreads();
    for (int i = tid; i < K_BUCK; i += 256) cnt[i * PART_B + blockIdx.x] = lcnt[i];
}

__global__ __launch_bounds__(256) void partition_kernel(const int* __restrict__ src,
                                                        const int* __restrict__ dst,
                                                        const int* __restrict__ base,
                                                        uint2* __restrict__ P) {
    __shared__ int lofs[K_BUCK];
    int tid = threadIdx.x;
    for (int i = tid; i < K_BUCK; i += 256) lofs[i] = base[i * PART_B + blockIdx.x];
    __syncthreads();
    int start = blockIdx.x * CHUNK;
    for (int it = tid; it < CHUNK; it += 256) {
        int e = start + it;
        int d = dst[e], s = src[e];
        int p = atomicAdd(&lofs[d >> 8], 1);
        P[p] = make_uint2((unsigned)d, (unsigned)s);
    }
}

// one block per bucket: derive rowptr from deg (LDS scan), then scatter col
__global__ __launch_bounds__(256) void fine_scatter_kernel(const uint2* __restrict__ P,
                                                           const int* __restrict__ base,
                                                           const int* __restrict__ deg,
                                                           int* __restrict__ rowptr,
                                                           int* __restrict__ col) {
    __shared__ int wloc[256];
    int b = blockIdx.x;
    int tid = threadIdx.x;
    int nbase = b << 8;
    int nn = min(256, N_NODES - nbase);
    int d = (tid < nn) ? deg[nbase + tid] : 0;
    int total;
    int excl = block_exscan256(d, tid, &total);
    int start = base[b * PART_B];
    int rp = start + excl;
    if (tid < nn) {
        rowptr[nbase + tid] = rp;
        wloc[tid] = rp;
    }
    if (b == K_BUCK - 1 && tid == 0) rowptr[N_NODES] = N_EDGES;
    __syncthreads();
    int end = (b + 1 < K_BUCK) ? base[(b + 1) * PART_B] : N_EDGES;
    for (int e = start + tid; e < end; e += 256) {
        uint2 pr = P[e];
        int rank = atomicAdd(&wloc[pr.x - nbase], 1);
        col[rank] = (int)pr.y;
    }
}

// ---------------- conversions ----------------

struct WT8 {
    const float* src[8];
    unsigned short* dst[8];
    int K[8];
    int N[8];
};

__global__ __launch_bounds__(256) void wtconv_kernel(WT8 p) {
    int wi = blockIdx.y;
    int K = p.K[wi], N = p.N[wi];
    int idx = blockIdx.x * 256 + threadIdx.x;
    if (idx >= K * N) return;
    int logn = 31 - __clz(N);
    int n = idx & (N - 1);
    int k = idx >> logn;
    p.dst[wi][(size_t)n * K + k] = f2bf(p.src[wi][idx]);
}

// ---------------- aggregation (bf16) ----------------

__device__ inline void acc8(uint4 v, float* a) {
    a[0] += bf2f(v.x & 0xFFFFu); a[1] += __uint_as_float(v.x & 0xFFFF0000u);
    a[2] += bf2f(v.y & 0xFFFFu); a[3] += __uint_as_float(v.y & 0xFFFF0000u);
    a[4] += bf2f(v.z & 0xFFFFu); a[5] += __uint_as_float(v.z & 0xFFFF0000u);
    a[6] += bf2f(v.w & 0xFFFFu); a[7] += __uint_as_float(v.w & 0xFFFF0000u);
}

template <int LPN, bool RELU>
__global__ __launch_bounds__(256) void aggregate_bf16_kernel(
    const unsigned short* __restrict__ h, const int* __restrict__ rowptr,
    const int* __restrict__ col, const float* __restrict__ bias,
    unsigned short* __restrict__ z, int n) {
    const int gpb = 256 / LPN;
    int gid = threadIdx.x / LPN;
    int l = threadIdx.x % LPN;
    int node = blockIdx.x * gpb + gid;
    if (node >= n) return;
    const uint4* hv = (const uint4*)h;
    float a[8] = {};
    acc8(hv[(size_t)node * LPN + l], a);  // self
    int s = rowptr[node], epos = rowptr[node + 1];
    for (int e = s; e < epos; ++e) {
        int j = col[e];
        acc8(hv[(size_t)j * LPN + l], a);
    }
    if (RELU) {
        float4 b0 = *(const float4*)(bias + l * 8);
        float4 b1 = *(const float4*)(bias + l * 8 + 4);
        a[0] = fmaxf(a[0] + b0.x, 0.f); a[1] = fmaxf(a[1] + b0.y, 0.f);
        a[2] = fmaxf(a[2] + b0.z, 0.f); a[3] = fmaxf(a[3] + b0.w, 0.f);
        a[4] = fmaxf(a[4] + b1.x, 0.f); a[5] = fmaxf(a[5] + b1.y, 0.f);
        a[6] = fmaxf(a[6] + b1.z, 0.f); a[7] = fmaxf(a[7] + b1.w, 0.f);
    }
    uint4 o;
    o.x = (unsigned int)f2bf(a[0]) | ((unsigned int)f2bf(a[1]) << 16);
    o.y = (unsigned int)f2bf(a[2]) | ((unsigned int)f2bf(a[3]) << 16);
    o.z = (unsigned int)f2bf(a[4]) | ((unsigned int)f2bf(a[5]) << 16);
    o.w = (unsigned int)f2bf(a[6]) | ((unsigned int)f2bf(a[7]) << 16);
    ((uint4*)z)[(size_t)node * LPN + l] = o;
}

// ---------------- bf16 MFMA GEMM v2 + XCD swizzle (+ optional fused classifier) ----
// C = epilogue(A @ Wt^T). A: M x K (bf16, or fp32 if F32A). Wt: Nn x K bf16.
// BM=128, BK=64, BN=NT*16. 1D swizzled grid: xcd = x&7 so all y-tiles of one
// row-tile land on the same XCD (A served from that XCD's L2, not HBM).
// mode 0: relu(acc+b); 1: relu((acc+b-mu)*g*rsqrt(var+eps)+be); 2: raw acc.
// CLS: after epilogue, compute out = h @ wcls + bcls (K=64, Nout=2) from LDS,
//      skip the C store.

template <int NT, bool F32A, bool CLS>
__global__ __launch_bounds__(256) void mfma_gemm2_kernel(
    const void* __restrict__ Ain, const unsigned short* __restrict__ Wt,
    const float* __restrict__ bias, unsigned short* __restrict__ C,
    int M, int K, int Nn, int mode, int gxblocks, int gy,
    const float* __restrict__ g, const float* __restrict__ be,
    const float* __restrict__ mu, const float* __restrict__ var,
    const float* __restrict__ wcls, const float* __restrict__ bcls,
    float* __restrict__ outp) {
    constexpr int BM = 128, BK = 64;
    constexpr int BN = NT * 16;
    constexpr int LDA = BK + 8;
    constexpr int LDB = BK + 8;
    constexpr int LDE = BN + 8;
    constexpr int NB_LD = (BN * BK / 8) / 256;
    __shared__ __align__(16) unsigned short smem[BM * LDA + BN * LDB];
    unsigned short* As = smem;
    unsigned short* Bs = smem + BM * LDA;
    unsigned short* Ep = smem;

    // swizzled decode: id = (x&7) + 8*(y + gy*(x>>3))
    int id = blockIdx.x;
    int lo = id & 7;
    int t = id >> 3;
    int y = t % gy;
    int x = ((t / gy) << 3) | lo;
    if (x >= gxblocks) return;

    const int tid = threadIdx.x;
    const int wv = tid >> 6;
    const int ln = tid & 63;
    const int l15 = ln & 15;
    const int quad = ln >> 4;
    const int row0 = x * BM;
    const int col0 = y * BN;

    const unsigned short* A16 = (const unsigned short*)Ain;
    const float* A32 = (const float*)Ain;

    uint4 Ar[4], Br[NB_LD];

    auto loadA = [&](int k0) {
#pragma unroll
        for (int u = 0; u < 4; ++u) {
            int idx2 = tid + 256 * u;
            int r = idx2 >> 3, cg = (idx2 & 7) * 8;
            int gr = row0 + r;
            if (gr >= M) gr = M - 1;  // clamp; OOB rows never stored
            if (F32A) {
                float4 f0 = *(const float4*)(A32 + (size_t)gr * K + k0 + cg);
                float4 f1 = *(const float4*)(A32 + (size_t)gr * K + k0 + cg + 4);
                uint4 o;
                o.x = (unsigned)f2bf(f0.x) | ((unsigned)f2bf(f0.y) << 16);
                o.y = (unsigned)f2bf(f0.z) | ((unsigned)f2bf(f0.w) << 16);
                o.z = (unsigned)f2bf(f1.x) | ((unsigned)f2bf(f1.y) << 16);
                o.w = (unsigned)f2bf(f1.z) | ((unsigned)f2bf(f1.w) << 16);
                Ar[u] = o;
            } else {
                Ar[u] = *(const uint4*)(A16 + (size_t)gr * K + k0 + cg);
            }
        }
    };
    auto loadB = [&](int k0) {
#pragma unroll
        for (int u = 0; u < NB_LD; ++u) {
            int idx2 = tid + 256 * u;
            int r = idx2 >> 3, cg = (idx2 & 7) * 8;
            Br[u] = *(const uint4*)(Wt + (size_t)(col0 + r) * K + k0 + cg);
        }
    };
    auto stage = [&]() {
#pragma unroll
        for (int u = 0; u < 4; ++u) {
            int idx2 = tid + 256 * u;
            int r = idx2 >> 3, cg = (idx2 & 7) * 8;
            *(uint4*)(&As[r * LDA + cg]) = Ar[u];
        }
#pragma unroll
        for (int u = 0; u < NB_LD; ++u) {
            int idx2 = tid + 256 * u;
            int r = idx2 >> 3, cg = (idx2 & 7) * 8;
            *(uint4*)(&Bs[r * LDB + cg]) = Br[u];
        }
    };

    f32x4 acc[2][NT] = {};
    const int KT = K >> 6;
    loadA(0);
    loadB(0);
    for (int kt = 0; kt < KT; ++kt) {
        if (kt > 0) __syncthreads();
        stage();
        __syncthreads();
        if (kt + 1 < KT) {
            loadA((kt + 1) * 64);
            loadB((kt + 1) * 64);
        }
#pragma unroll
        for (int kh = 0; kh < 2; ++kh) {
            bshort8 af[2];
#pragma unroll
            for (int mt = 0; mt < 2; ++mt)
                af[mt] = *(const bshort8*)(&As[(wv * 32 + mt * 16 + l15) * LDA + kh * 32 + quad * 8]);
#pragma unroll
            for (int nt = 0; nt < NT; ++nt) {
                bshort8 bf = *(const bshort8*)(&Bs[(nt * 16 + l15) * LDB + kh * 32 + quad * 8]);
                acc[0][nt] = __builtin_amdgcn_mfma_f32_16x16x32_bf16(af[0], bf, acc[0][nt], 0, 0, 0);
                acc[1][nt] = __builtin_amdgcn_mfma_f32_16x16x32_bf16(af[1], bf, acc[1][nt], 0, 0, 0);
            }
        }
    }

    // epilogue: scale/shift/relu -> LDS
    __syncthreads();
#pragma unroll
    for (int nt = 0; nt < NT; ++nt) {
        int c = col0 + nt * 16 + l15;
        float s = 1.f, sh = 0.f;
        if (mode == 0) {
            sh = bias[c];
        } else if (mode == 1) {
            float tt = g[c] * rsqrtf(var[c] + BN_EPS);
            s = tt;
            sh = be[c] - mu[c] * tt + bias[c] * tt;
        }
#pragma unroll
        for (int mt = 0; mt < 2; ++mt) {
            int rl = wv * 32 + mt * 16 + quad * 4;
#pragma unroll
            for (int r = 0; r < 4; ++r) {
                float v = acc[mt][nt][r] * s + sh;
                if (mode != 2) v = fmaxf(v, 0.f);
                Ep[(rl + r) * LDE + nt * 16 + l15] = f2bf(v);
            }
        }
    }
    __syncthreads();
    if (CLS) {
        // fused classifier: out[row] = h[row] @ wcls + bcls (BN==64)
        int r = tid >> 1, j = tid & 1;
        int grow = row0 + r;
        if (grow < M) {
            float s = 0.f;
#pragma unroll 8
            for (int k = 0; k < 64; ++k)
                s += bf2f(Ep[r * LDE + k]) * wcls[k * 2 + j];
            outp[(size_t)grow * 2 + j] = s + bcls[j];
        }
    } else {
        constexpr int CGR = BN / 8;
        constexpr int NU = BM * CGR / 256;
#pragma unroll
        for (int u = 0; u < NU; ++u) {
            int idx2 = tid + 256 * u;
            int r = idx2 / CGR, cg = (idx2 % CGR) * 8;
            int grow = row0 + r;
            if (grow < M)
                *(uint4*)(C + (size_t)grow * Nn + col0 + cg) = *(const uint4*)(&Ep[r * LDE + cg]);
        }
    }
}

// ---------------- launch ----------------

extern "C" void kernel_launch(void* const* d_in, const int* in_sizes, int n_in,
                              void* d_out, int out_size, void* d_ws, size_t ws_size,
                              hipStream_t stream) {
    const float* x = (const float*)d_in[0];
    const int* ei = (const int*)d_in[1];
    const int* src = ei;
    const int* dst = ei + N_EDGES;
    const float* w[4][2];
    const float* b[4][2];
    const float* bng[4];
    const float* bnb[4];
    const float* bnm[4];
    const float* bnv[4];
    int idx = 2;
    for (int i = 0; i < 4; ++i) {
        w[i][0] = (const float*)d_in[idx++];
        b[i][0] = (const float*)d_in[idx++];
        w[i][1] = (const float*)d_in[idx++];
        b[i][1] = (const float*)d_in[idx++];
        bng[i] = (const float*)d_in[idx++];
        bnb[i] = (const float*)d_in[idx++];
        bnm[i] = (const float*)d_in[idx++];
        bnv[i] = (const float*)d_in[idx++];
    }
    const float* wc = (const float*)d_in[idx++];
    const float* bc = (const float*)d_in[idx++];
    float* out = (float*)d_out;

    char* ws = (char*)d_ws;
    size_t off = 0;
    auto alloc = [&](size_t bytes) {
        char* p = ws + off;
        off = (off + bytes + 255) & ~(size_t)255;
        return p;
    };
    int* deg = (int*)alloc((size_t)N_NODES * 4);
    int* rowptr = (int*)alloc((size_t)(N_NODES + 1) * 4);
    int* cnt = (int*)alloc((size_t)K_BUCK * PART_B * 4);
    int* bsum2 = (int*)alloc((size_t)K_BUCK * 4);
    int* col = (int*)alloc((size_t)N_EDGES * 4);
    uint2* P = (uint2*)alloc((size_t)N_EDGES * 8);
    unsigned short* bufA = (unsigned short*)alloc((size_t)N_NODES * 256 * 2);
    unsigned short* bufB = (unsigned short*)alloc((size_t)N_NODES * 256 * 2);
    unsigned short* bufC = (unsigned short*)alloc((size_t)N_NODES * 256 * 2);
    const int dims_in[4] = {256, 128, 256, 128};
    const int dims_h[4] = {128, 256, 128, 64};
    unsigned short* wt[4][2];
    for (int L = 0; L < 4; ++L) {
        wt[L][0] = (unsigned short*)alloc((size_t)dims_in[L] * dims_h[L] * 2);
        wt[L][1] = (unsigned short*)alloc((size_t)dims_h[L] * dims_h[L] * 2);
    }
    (void)ws_size;

    // weight transpose-convert
    WT8 p;
    for (int L = 0; L < 4; ++L) {
        p.src[L * 2] = w[L][0];     p.dst[L * 2] = wt[L][0];
        p.K[L * 2] = dims_in[L];    p.N[L * 2] = dims_h[L];
        p.src[L * 2 + 1] = w[L][1]; p.dst[L * 2 + 1] = wt[L][1];
        p.K[L * 2 + 1] = dims_h[L]; p.N[L * 2 + 1] = dims_h[L];
    }
    wtconv_kernel<<<dim3(256, 8), 256, 0, stream>>>(p);

    // ---- CSR build (fused: 7 dispatches) ----
    hipMemsetAsync(deg, 0, (size_t)N_NODES * 4, stream);
    bucket_count_kernel<<<PART_B, 256, 0, stream>>>(dst, deg, cnt);
    scan_reduce_kernel<<<K_BUCK, 256, 0, stream>>>(cnt, bsum2, K_BUCK * PART_B);
    scan_bsum_kernel<<<1, 256, 0, stream>>>(bsum2, K_BUCK);
    scan_apply_kernel<<<K_BUCK, 256, 0, stream>>>(cnt, bsum2, cnt, K_BUCK * PART_B);
    partition_kernel<<<PART_B, 256, 0, stream>>>(src, dst, cnt, P);
    fine_scatter_kernel<<<K_BUCK, 256, 0, stream>>>(P, cnt, deg, rowptr, col);

    const int gx = (N_NODES + 127) / 128;       // 391
    const int gxp = ((gx + 7) / 8) * 8;         // 392 (swizzle padding)
    const int M = N_NODES;

    // ---- Layer 1 (commuted: GEMM1 256->128 reads fp32 x, agg@128+bias+relu, GEMM2) ----
    mfma_gemm2_kernel<8, true, false><<<gxp * 1, 256, 0, stream>>>(
        x, wt[0][0], nullptr, bufA, M, 256, 128, 2, gx, 1,
        nullptr, nullptr, nullptr, nullptr, nullptr, nullptr, nullptr);
    aggregate_bf16_kernel<16, true><<<(N_NODES + 15) / 16, 256, 0, stream>>>(
        bufA, rowptr, col, b[0][0], bufB, N_NODES);
    mfma_gemm2_kernel<8, false, false><<<gxp * 1, 256, 0, stream>>>(
        bufB, wt[0][1], b[0][1], bufC, M, 128, 128, 1, gx, 1,
        bng[0], bnb[0], bnm[0], bnv[0], nullptr, nullptr, nullptr);

    // ---- Layer 2 (agg-first: agg@128, GEMM1 128->256 relu, GEMM2 256->256 BN) ----
    aggregate_bf16_kernel<16, false><<<(N_NODES + 15) / 16, 256, 0, stream>>>(
        bufC, rowptr, col, nullptr, bufA, N_NODES);
    mfma_gemm2_kernel<8, false, false><<<gxp * 2, 256, 0, stream>>>(
        bufA, wt[1][0], b[1][0], bufB, M, 128, 256, 0, gx, 2,
        nullptr, nullptr, nullptr, nullptr, nullptr, nullptr, nullptr);
    mfma_gemm2_kernel<8, false, false><<<gxp * 2, 256, 0, stream>>>(
        bufB, wt[1][1], b[1][1], bufC, M, 256, 256, 1, gx, 2,
        bng[1], bnb[1], bnm[1], bnv[1], nullptr, nullptr, nullptr);

    // ---- Layer 3 (commuted: GEMM1 256->128, agg@128+bias+relu, GEMM2) ----
    mfma_gemm2_kernel<8, false, false><<<gxp * 1, 256, 0, stream>>>(
        bufC, wt[2][0], nullptr, bufA, M, 256, 128, 2, gx, 1,
        nullptr, nullptr, nullptr, nullptr, nullptr, nullptr, nullptr);
    aggregate_bf16_kernel<16, true><<<(N_NODES + 15) / 16, 256, 0, stream>>>(
        bufA, rowptr, col, b[2][0], bufB, N_NODES);
    mfma_gemm2_kernel<8, false, false><<<gxp * 1, 256, 0, stream>>>(
        bufB, wt[2][1], b[2][1], bufC, M, 128, 128, 1, gx, 1,
        bng[2], bnb[2], bnm[2], bnv[2], nullptr, nullptr, nullptr);

    // ---- Layer 4 (commuted: GEMM1 128->64, agg@64+bias+relu, GEMM2+classifier) ----
    mfma_gemm2_kernel<4, false, false><<<gxp * 1, 256, 0, stream>>>(
        bufC, wt[3][0], nullptr, bufA, M, 128, 64, 2, gx, 1,
        nullptr, nullptr, nullptr, nullptr, nullptr, nullptr, nullptr);
    aggregate_bf16_kernel<8, true><<<(N_NODES + 31) / 32, 256, 0, stream>>>(
        bufA, rowptr, col, b[3][0], bufB, N_NODES);
    mfma_gemm2_kernel<4, false, true><<<gxp * 1, 256, 0, stream>>>(
        bufB, wt[3][1], b[3][1], nullptr, M, 64, 64, 1, gx, 1,
        bng[3], bnb[3], bnm[3], bnv[3], wc, bc, out);
}

// Round 9
// 510.465 us; speedup vs baseline: 1.1698x; 1.0377x over previous
//
#include <hip/hip_runtime.h>

#define N_NODES 50000
#define N_EDGES 800000
#define BN_EPS 1e-5f
#define K_BUCK 196        // dst >> 8 buckets (256 nodes each)
#define PART_B 256        // partition blocks
#define CHUNK 3125        // N_EDGES / PART_B

typedef __attribute__((ext_vector_type(8))) short bshort8;
typedef __attribute__((ext_vector_type(4))) float f32x4;

__device__ inline float bf2f(unsigned int u16) {
    return __uint_as_float(u16 << 16);
}
__device__ inline unsigned short f2bf(float f) {
    unsigned int u = __float_as_uint(f);
    u = (u + 0x7FFFu + ((u >> 16) & 1u)) >> 16;
    return (unsigned short)u;
}

// ---------------- scan helpers ----------------

__device__ inline int block_exscan256(int v, int tid, int* total) {
    int lane = tid & 63;
    int wave = tid >> 6;
    int incl = v;
#pragma unroll
    for (int off = 1; off < 64; off <<= 1) {
        int t = __shfl_up(incl, off, 64);
        if (lane >= off) incl += t;
    }
    __shared__ int wsum[4];
    if (lane == 63) wsum[wave] = incl;
    __syncthreads();
    int w0 = wsum[0], w1 = wsum[1], w2 = wsum[2], w3 = wsum[3];
    __syncthreads();
    int wofs = (wave > 0 ? w0 : 0) + (wave > 1 ? w1 : 0) + (wave > 2 ? w2 : 0);
    *total = w0 + w1 + w2 + w3;
    return wofs + incl - v;
}

__global__ __launch_bounds__(256) void scan_reduce_kernel(const int* __restrict__ in,
                                                          int* __restrict__ bsum, int n) {
    int tid = threadIdx.x;
    int i = blockIdx.x * 256 + tid;
    int v = (i < n) ? in[i] : 0;
    int lane = tid & 63;
    int wave = tid >> 6;
#pragma unroll
    for (int off = 32; off > 0; off >>= 1) v += __shfl_down(v, off, 64);
    __shared__ int wsum[4];
    if (lane == 0) wsum[wave] = v;
    __syncthreads();
    if (tid == 0) bsum[blockIdx.x] = wsum[0] + wsum[1] + wsum[2] + wsum[3];
}

__global__ __launch_bounds__(256) void scan_bsum_kernel(int* __restrict__ bsum, int B) {
    int tid = threadIdx.x;
    int v = (tid < B) ? bsum[tid] : 0;
    int total;
    int excl = block_exscan256(v, tid, &total);
    if (tid < B) bsum[tid] = excl;
}

__global__ __launch_bounds__(256) void scan_apply_kernel(const int* __restrict__ in,
                                                         const int* __restrict__ bsum,
                                                         int* __restrict__ out, int n) {
    int tid = threadIdx.x;
    int i = blockIdx.x * 256 + tid;
    int v = (i < n) ? in[i] : 0;
    int total;
    int excl = block_exscan256(v, tid, &total);
    if (i < n) out[i] = bsum[blockIdx.x] + excl;
}

// ---- bucketed CSR build ----

__global__ __launch_bounds__(256) void bucket_count_kernel(const int* __restrict__ dst,
                                                           int* __restrict__ deg,
                                                           int* __restrict__ cnt) {
    __shared__ int lcnt[K_BUCK];
    int tid = threadIdx.x;
    for (int i = tid; i < K_BUCK; i += 256) lcnt[i] = 0;
    __syncthreads();
    int start = blockIdx.x * CHUNK;
    for (int it = tid; it < CHUNK; it += 256) {
        int d = dst[start + it];
        atomicAdd(&lcnt[d >> 8], 1);
        atomicAdd(&deg[d], 1);
    }
    __syncthreads();
    for (int i = tid; i < K_BUCK; i += 256) cnt[i * PART_B + blockIdx.x] = lcnt[i];
}

__global__ __launch_bounds__(256) void partition_kernel(const int* __restrict__ src,
                                                        const int* __restrict__ dst,
                                                        const int* __restrict__ base,
                                                        uint2* __restrict__ P) {
    __shared__ int lofs[K_BUCK];
    int tid = threadIdx.x;
    for (int i = tid; i < K_BUCK; i += 256) lofs[i] = base[i * PART_B + blockIdx.x];
    __syncthreads();
    int start = blockIdx.x * CHUNK;
    for (int it = tid; it < CHUNK; it += 256) {
        int e = start + it;
        int d = dst[e], s = src[e];
        int p = atomicAdd(&lofs[d >> 8], 1);
        P[p] = make_uint2((unsigned)d, (unsigned)s);
    }
}

__global__ __launch_bounds__(256) void fine_scatter_kernel(const uint2* __restrict__ P,
                                                           const int* __restrict__ base,
                                                           const int* __restrict__ deg,
                                                           int* __restrict__ rowptr,
                                                           int* __restrict__ col) {
    __shared__ int wloc[256];
    int b = blockIdx.x;
    int tid = threadIdx.x;
    int nbase = b << 8;
    int nn = min(256, N_NODES - nbase);
    int d = (tid < nn) ? deg[nbase + tid] : 0;
    int total;
    int excl = block_exscan256(d, tid, &total);
    int start = base[b * PART_B];
    int rp = start + excl;
    if (tid < nn) {
        rowptr[nbase + tid] = rp;
        wloc[tid] = rp;
    }
    if (b == K_BUCK - 1 && tid == 0) rowptr[N_NODES] = N_EDGES;
    __syncthreads();
    int end = (b + 1 < K_BUCK) ? base[(b + 1) * PART_B] : N_EDGES;
    for (int e = start + tid; e < end; e += 256) {
        uint2 pr = P[e];
        int rank = atomicAdd(&wloc[pr.x - nbase], 1);
        col[rank] = (int)pr.y;
    }
}

// ---------------- conversions ----------------

struct WT8 {
    const float* src[8];
    unsigned short* dst[8];
    int K[8];
    int N[8];
};

__global__ __launch_bounds__(256) void wtconv_kernel(WT8 p) {
    int wi = blockIdx.y;
    int K = p.K[wi], N = p.N[wi];
    int idx = blockIdx.x * 256 + threadIdx.x;
    if (idx >= K * N) return;
    int logn = 31 - __clz(N);
    int n = idx & (N - 1);
    int k = idx >> logn;
    p.dst[wi][(size_t)n * K + k] = f2bf(p.src[wi][idx]);
}

// ---------------- aggregation (bf16) ----------------

__device__ inline void acc8(uint4 v, float* a) {
    a[0] += bf2f(v.x & 0xFFFFu); a[1] += __uint_as_float(v.x & 0xFFFF0000u);
    a[2] += bf2f(v.y & 0xFFFFu); a[3] += __uint_as_float(v.y & 0xFFFF0000u);
    a[4] += bf2f(v.z & 0xFFFFu); a[5] += __uint_as_float(v.z & 0xFFFF0000u);
    a[6] += bf2f(v.w & 0xFFFFu); a[7] += __uint_as_float(v.w & 0xFFFF0000u);
}

template <int LPN, bool RELU>
__global__ __launch_bounds__(256) void aggregate_bf16_kernel(
    const unsigned short* __restrict__ h, const int* __restrict__ rowptr,
    const int* __restrict__ col, const float* __restrict__ bias,
    unsigned short* __restrict__ z, int n) {
    const int gpb = 256 / LPN;
    int gid = threadIdx.x / LPN;
    int l = threadIdx.x % LPN;
    int node = blockIdx.x * gpb + gid;
    if (node >= n) return;
    const uint4* hv = (const uint4*)h;
    float a[8] = {};
    acc8(hv[(size_t)node * LPN + l], a);  // self
    int s = rowptr[node], epos = rowptr[node + 1];
    for (int e = s; e < epos; ++e) {
        int j = col[e];
        acc8(hv[(size_t)j * LPN + l], a);
    }
    if (RELU) {
        float4 b0 = *(const float4*)(bias + l * 8);
        float4 b1 = *(const float4*)(bias + l * 8 + 4);
        a[0] = fmaxf(a[0] + b0.x, 0.f); a[1] = fmaxf(a[1] + b0.y, 0.f);
        a[2] = fmaxf(a[2] + b0.z, 0.f); a[3] = fmaxf(a[3] + b0.w, 0.f);
        a[4] = fmaxf(a[4] + b1.x, 0.f); a[5] = fmaxf(a[5] + b1.y, 0.f);
        a[6] = fmaxf(a[6] + b1.z, 0.f); a[7] = fmaxf(a[7] + b1.w, 0.f);
    }
    uint4 o;
    o.x = (unsigned int)f2bf(a[0]) | ((unsigned int)f2bf(a[1]) << 16);
    o.y = (unsigned int)f2bf(a[2]) | ((unsigned int)f2bf(a[3]) << 16);
    o.z = (unsigned int)f2bf(a[4]) | ((unsigned int)f2bf(a[5]) << 16);
    o.w = (unsigned int)f2bf(a[6]) | ((unsigned int)f2bf(a[7]) << 16);
    ((uint4*)z)[(size_t)node * LPN + l] = o;
}

// ---------------- epilogue scale/shift helper ----------------
// mode 0: relu(v+b); 1: relu((v+b-mu)*g*rsqrt(var+eps)+be); 2: raw

__device__ inline void epi_coeff(int mode, int c, const float* bias, const float* g,
                                 const float* be, const float* mu, const float* var,
                                 float* s, float* sh) {
    *s = 1.f; *sh = 0.f;
    if (mode == 0) {
        *sh = bias[c];
    } else if (mode == 1) {
        float t = g[c] * rsqrtf(var[c] + BN_EPS);
        *s = t;
        *sh = be[c] - mu[c] * t + bias[c] * t;
    }
}

// ---------------- bf16 MFMA GEMM v2 + XCD swizzle (+ optional fused classifier) ----

template <int NT, bool F32A, bool CLS>
__global__ __launch_bounds__(256) void mfma_gemm2_kernel(
    const void* __restrict__ Ain, const unsigned short* __restrict__ Wt,
    const float* __restrict__ bias, unsigned short* __restrict__ C,
    int M, int K, int Nn, int mode, int gxblocks, int gy,
    const float* __restrict__ g, const float* __restrict__ be,
    const float* __restrict__ mu, const float* __restrict__ var,
    const float* __restrict__ wcls, const float* __restrict__ bcls,
    float* __restrict__ outp) {
    constexpr int BM = 128, BK = 64;
    constexpr int BN = NT * 16;
    constexpr int LDA = BK + 8;
    constexpr int LDB = BK + 8;
    constexpr int LDE = BN + 8;
    constexpr int NB_LD = (BN * BK / 8) / 256;
    __shared__ __align__(16) unsigned short smem[BM * LDA + BN * LDB];
    unsigned short* As = smem;
    unsigned short* Bs = smem + BM * LDA;
    unsigned short* Ep = smem;

    int id = blockIdx.x;
    int lo = id & 7;
    int t = id >> 3;
    int y = t % gy;
    int x = ((t / gy) << 3) | lo;
    if (x >= gxblocks) return;

    const int tid = threadIdx.x;
    const int wv = tid >> 6;
    const int ln = tid & 63;
    const int l15 = ln & 15;
    const int quad = ln >> 4;
    const int row0 = x * BM;
    const int col0 = y * BN;

    const unsigned short* A16 = (const unsigned short*)Ain;
    const float* A32 = (const float*)Ain;

    uint4 Ar[4], Br[NB_LD];

    auto loadA = [&](int k0) {
#pragma unroll
        for (int u = 0; u < 4; ++u) {
            int idx2 = tid + 256 * u;
            int r = idx2 >> 3, cg = (idx2 & 7) * 8;
            int gr = row0 + r;
            if (gr >= M) gr = M - 1;
            if (F32A) {
                float4 f0 = *(const float4*)(A32 + (size_t)gr * K + k0 + cg);
                float4 f1 = *(const float4*)(A32 + (size_t)gr * K + k0 + cg + 4);
                uint4 o;
                o.x = (unsigned)f2bf(f0.x) | ((unsigned)f2bf(f0.y) << 16);
                o.y = (unsigned)f2bf(f0.z) | ((unsigned)f2bf(f0.w) << 16);
                o.z = (unsigned)f2bf(f1.x) | ((unsigned)f2bf(f1.y) << 16);
                o.w = (unsigned)f2bf(f1.z) | ((unsigned)f2bf(f1.w) << 16);
                Ar[u] = o;
            } else {
                Ar[u] = *(const uint4*)(A16 + (size_t)gr * K + k0 + cg);
            }
        }
    };
    auto loadB = [&](int k0) {
#pragma unroll
        for (int u = 0; u < NB_LD; ++u) {
            int idx2 = tid + 256 * u;
            int r = idx2 >> 3, cg = (idx2 & 7) * 8;
            Br[u] = *(const uint4*)(Wt + (size_t)(col0 + r) * K + k0 + cg);
        }
    };
    auto stage = [&]() {
#pragma unroll
        for (int u = 0; u < 4; ++u) {
            int idx2 = tid + 256 * u;
            int r = idx2 >> 3, cg = (idx2 & 7) * 8;
            *(uint4*)(&As[r * LDA + cg]) = Ar[u];
        }
#pragma unroll
        for (int u = 0; u < NB_LD; ++u) {
            int idx2 = tid + 256 * u;
            int r = idx2 >> 3, cg = (idx2 & 7) * 8;
            *(uint4*)(&Bs[r * LDB + cg]) = Br[u];
        }
    };

    f32x4 acc[2][NT] = {};
    const int KT = K >> 6;
    loadA(0);
    loadB(0);
    for (int kt = 0; kt < KT; ++kt) {
        if (kt > 0) __syncthreads();
        stage();
        __syncthreads();
        if (kt + 1 < KT) {
            loadA((kt + 1) * 64);
            loadB((kt + 1) * 64);
        }
#pragma unroll
        for (int kh = 0; kh < 2; ++kh) {
            bshort8 af[2];
#pragma unroll
            for (int mt = 0; mt < 2; ++mt)
                af[mt] = *(const bshort8*)(&As[(wv * 32 + mt * 16 + l15) * LDA + kh * 32 + quad * 8]);
#pragma unroll
            for (int nt = 0; nt < NT; ++nt) {
                bshort8 bf = *(const bshort8*)(&Bs[(nt * 16 + l15) * LDB + kh * 32 + quad * 8]);
                acc[0][nt] = __builtin_amdgcn_mfma_f32_16x16x32_bf16(af[0], bf, acc[0][nt], 0, 0, 0);
                acc[1][nt] = __builtin_amdgcn_mfma_f32_16x16x32_bf16(af[1], bf, acc[1][nt], 0, 0, 0);
            }
        }
    }

    __syncthreads();
#pragma unroll
    for (int nt = 0; nt < NT; ++nt) {
        int c = col0 + nt * 16 + l15;
        float s, sh;
        epi_coeff(mode, c, bias, g, be, mu, var, &s, &sh);
#pragma unroll
        for (int mt = 0; mt < 2; ++mt) {
            int rl = wv * 32 + mt * 16 + quad * 4;
#pragma unroll
            for (int r = 0; r < 4; ++r) {
                float v = acc[mt][nt][r] * s + sh;
                if (mode != 2) v = fmaxf(v, 0.f);
                Ep[(rl + r) * LDE + nt * 16 + l15] = f2bf(v);
            }
        }
    }
    __syncthreads();
    if (CLS) {
        int r = tid >> 1, j = tid & 1;
        int grow = row0 + r;
        if (grow < M) {
            float s = 0.f;
#pragma unroll 8
            for (int k = 0; k < 64; ++k)
                s += bf2f(Ep[r * LDE + k]) * wcls[k * 2 + j];
            outp[(size_t)grow * 2 + j] = s + bcls[j];
        }
    } else {
        constexpr int CGR = BN / 8;
        constexpr int NU = BM * CGR / 256;
#pragma unroll
        for (int u = 0; u < NU; ++u) {
            int idx2 = tid + 256 * u;
            int r = idx2 / CGR, cg = (idx2 % CGR) * 8;
            int grow = row0 + r;
            if (grow < M)
                *(uint4*)(C + (size_t)grow * Nn + col0 + cg) = *(const uint4*)(&Ep[r * LDE + cg]);
        }
    }
}

// ---------------- fused 2-stage MLP GEMM ----------------
// C = epi2( epi1(A @ Wt1^T) @ Wt2^T ). A: M x KIN bf16. Wt1: DH1 x KIN.
// Wt2: DH2 x DH1. BM=64 per block (full output width -> zero A-refetch).
// T1 lives in LDS; stage-2 A-fragments come from LDS (no global dependency).
// B fragments read direct from L2-hot weights.

template <int KIN, int DH1, int DH2>
__global__ __launch_bounds__(256) void fused_mlp_kernel(
    const unsigned short* __restrict__ A,
    const unsigned short* __restrict__ Wt1, const unsigned short* __restrict__ Wt2,
    int mode1, const float* __restrict__ b1, const float* __restrict__ g1,
    const float* __restrict__ be1, const float* __restrict__ mu1, const float* __restrict__ var1,
    int mode2, const float* __restrict__ b2, const float* __restrict__ g2,
    const float* __restrict__ be2, const float* __restrict__ mu2, const float* __restrict__ var2,
    unsigned short* __restrict__ C, int M) {
    constexpr int BM = 64, BK = 64;
    constexpr int LDA = BK + 8;
    constexpr int LT1 = DH1 + 8;
    constexpr int LDE = DH2 + 8;
    constexpr int NT1 = DH1 / 32;  // tiles per wave (half width), stage 1
    constexpr int NT2 = DH2 / 32;  // stage 2
    constexpr int KT = KIN / 64;
    __shared__ __align__(16) unsigned short As[BM * LDA];
    __shared__ __align__(16) unsigned short T1[BM * LT1];   // also reused as Ep

    const int tid = threadIdx.x;
    const int wv = tid >> 6;
    const int ln = tid & 63;
    const int l15 = ln & 15;
    const int quad = ln >> 4;
    const int rw = (wv >> 1) * 32;          // wave row base
    const int ch1 = (wv & 1) * (DH1 / 2);   // stage-1 col base
    const int ch2 = (wv & 1) * (DH2 / 2);   // stage-2 col base
    const int row0 = blockIdx.x * BM;

    uint4 Ar[2];
    auto loadA = [&](int k0) {
#pragma unroll
        for (int u = 0; u < 2; ++u) {
            int idx2 = tid + 256 * u;
            int r = idx2 >> 3, cg = (idx2 & 7) * 8;
            int gr = row0 + r;
            if (gr >= M) gr = M - 1;
            Ar[u] = *(const uint4*)(A + (size_t)gr * KIN + k0 + cg);
        }
    };
    auto stageA = [&]() {
#pragma unroll
        for (int u = 0; u < 2; ++u) {
            int idx2 = tid + 256 * u;
            int r = idx2 >> 3, cg = (idx2 & 7) * 8;
            *(uint4*)(&As[r * LDA + cg]) = Ar[u];
        }
    };

    // ---- stage 1 ----
    f32x4 acc1[2][NT1] = {};
    loadA(0);
    for (int kt = 0; kt < KT; ++kt) {
        if (kt > 0) __syncthreads();
        stageA();
        __syncthreads();
        if (kt + 1 < KT) loadA((kt + 1) * 64);
#pragma unroll
        for (int kh = 0; kh < 2; ++kh) {
            bshort8 af[2];
#pragma unroll
            for (int mt = 0; mt < 2; ++mt)
                af[mt] = *(const bshort8*)(&As[(rw + mt * 16 + l15) * LDA + kh * 32 + quad * 8]);
#pragma unroll
            for (int nt = 0; nt < NT1; ++nt) {
                bshort8 bf = *(const bshort8*)(Wt1 + (size_t)(ch1 + nt * 16 + l15) * KIN + kt * 64 + kh * 32 + quad * 8);
                acc1[0][nt] = __builtin_amdgcn_mfma_f32_16x16x32_bf16(af[0], bf, acc1[0][nt], 0, 0, 0);
                acc1[1][nt] = __builtin_amdgcn_mfma_f32_16x16x32_bf16(af[1], bf, acc1[1][nt], 0, 0, 0);
            }
        }
    }
    // epi1 -> T1 (LDS)
#pragma unroll
    for (int nt = 0; nt < NT1; ++nt) {
        int c = ch1 + nt * 16 + l15;
        float s, sh;
        epi_coeff(mode1, c, b1, g1, be1, mu1, var1, &s, &sh);
#pragma unroll
        for (int mt = 0; mt < 2; ++mt) {
            int rl = rw + mt * 16 + quad * 4;
#pragma unroll
            for (int r = 0; r < 4; ++r) {
                float v = acc1[mt][nt][r] * s + sh;
                if (mode1 != 2) v = fmaxf(v, 0.f);
                T1[(rl + r) * LT1 + c] = f2bf(v);
            }
        }
    }
    __syncthreads();

    // ---- stage 2: A-fragments from T1 (LDS), K2 = DH1 ----
    f32x4 acc2[2][NT2] = {};
#pragma unroll
    for (int ks = 0; ks < DH1 / 32; ++ks) {
        bshort8 af[2];
#pragma unroll
        for (int mt = 0; mt < 2; ++mt)
            af[mt] = *(const bshort8*)(&T1[(rw + mt * 16 + l15) * LT1 + ks * 32 + quad * 8]);
#pragma unroll
        for (int nt = 0; nt < NT2; ++nt) {
            bshort8 bf = *(const bshort8*)(Wt2 + (size_t)(ch2 + nt * 16 + l15) * DH1 + ks * 32 + quad * 8);
            acc2[0][nt] = __builtin_amdgcn_mfma_f32_16x16x32_bf16(af[0], bf, acc2[0][nt], 0, 0, 0);
            acc2[1][nt] = __builtin_amdgcn_mfma_f32_16x16x32_bf16(af[1], bf, acc2[1][nt], 0, 0, 0);
        }
    }
    __syncthreads();  // done reading T1; safe to overwrite as Ep

    // epi2 -> Ep (reuse T1 buffer) -> coalesced stores
    unsigned short* Ep = T1;
#pragma unroll
    for (int nt = 0; nt < NT2; ++nt) {
        int c = ch2 + nt * 16 + l15;
        float s, sh;
        epi_coeff(mode2, c, b2, g2, be2, mu2, var2, &s, &sh);
#pragma unroll
        for (int mt = 0; mt < 2; ++mt) {
            int rl = rw + mt * 16 + quad * 4;
#pragma unroll
            for (int r = 0; r < 4; ++r) {
                float v = acc2[mt][nt][r] * s + sh;
                if (mode2 != 2) v = fmaxf(v, 0.f);
                Ep[(rl + r) * LDE + c] = f2bf(v);
            }
        }
    }
    __syncthreads();
    constexpr int CGR = DH2 / 8;
    constexpr int NU = BM * CGR / 256;
#pragma unroll
    for (int u = 0; u < NU; ++u) {
        int idx2 = tid + 256 * u;
        int r = idx2 / CGR, cg = (idx2 % CGR) * 8;
        int grow = row0 + r;
        if (grow < M)
            *(uint4*)(C + (size_t)grow * DH2 + cg) = *(const uint4*)(&Ep[r * LDE + cg]);
    }
}

// ---------------- launch ----------------

extern "C" void kernel_launch(void* const* d_in, const int* in_sizes, int n_in,
                              void* d_out, int out_size, void* d_ws, size_t ws_size,
                              hipStream_t stream) {
    const float* x = (const float*)d_in[0];
    const int* ei = (const int*)d_in[1];
    const int* src = ei;
    const int* dst = ei + N_EDGES;
    const float* w[4][2];
    const float* b[4][2];
    const float* bng[4];
    const float* bnb[4];
    const float* bnm[4];
    const float* bnv[4];
    int idx = 2;
    for (int i = 0; i < 4; ++i) {
        w[i][0] = (const float*)d_in[idx++];
        b[i][0] = (const float*)d_in[idx++];
        w[i][1] = (const float*)d_in[idx++];
        b[i][1] = (const float*)d_in[idx++];
        bng[i] = (const float*)d_in[idx++];
        bnb[i] = (const float*)d_in[idx++];
        bnm[i] = (const float*)d_in[idx++];
        bnv[i] = (const float*)d_in[idx++];
    }
    const float* wc = (const float*)d_in[idx++];
    const float* bc = (const float*)d_in[idx++];
    float* out = (float*)d_out;

    char* ws = (char*)d_ws;
    size_t off = 0;
    auto alloc = [&](size_t bytes) {
        char* p = ws + off;
        off = (off + bytes + 255) & ~(size_t)255;
        return p;
    };
    int* deg = (int*)alloc((size_t)N_NODES * 4);
    int* rowptr = (int*)alloc((size_t)(N_NODES + 1) * 4);
    int* cnt = (int*)alloc((size_t)K_BUCK * PART_B * 4);
    int* bsum2 = (int*)alloc((size_t)K_BUCK * 4);
    int* col = (int*)alloc((size_t)N_EDGES * 4);
    uint2* P = (uint2*)alloc((size_t)N_EDGES * 8);
    unsigned short* bufA = (unsigned short*)alloc((size_t)N_NODES * 256 * 2);
    unsigned short* bufB = (unsigned short*)alloc((size_t)N_NODES * 256 * 2);
    unsigned short* bufC = (unsigned short*)alloc((size_t)N_NODES * 256 * 2);
    const int dims_in[4] = {256, 128, 256, 128};
    const int dims_h[4] = {128, 256, 128, 64};
    unsigned short* wt[4][2];
    for (int L = 0; L < 4; ++L) {
        wt[L][0] = (unsigned short*)alloc((size_t)dims_in[L] * dims_h[L] * 2);
        wt[L][1] = (unsigned short*)alloc((size_t)dims_h[L] * dims_h[L] * 2);
    }
    (void)ws_size;

    // weight transpose-convert
    WT8 p;
    for (int L = 0; L < 4; ++L) {
        p.src[L * 2] = w[L][0];     p.dst[L * 2] = wt[L][0];
        p.K[L * 2] = dims_in[L];    p.N[L * 2] = dims_h[L];
        p.src[L * 2 + 1] = w[L][1]; p.dst[L * 2 + 1] = wt[L][1];
        p.K[L * 2 + 1] = dims_h[L]; p.N[L * 2 + 1] = dims_h[L];
    }
    wtconv_kernel<<<dim3(256, 8), 256, 0, stream>>>(p);

    // ---- CSR build ----
    hipMemsetAsync(deg, 0, (size_t)N_NODES * 4, stream);
    bucket_count_kernel<<<PART_B, 256, 0, stream>>>(dst, deg, cnt);
    scan_reduce_kernel<<<K_BUCK, 256, 0, stream>>>(cnt, bsum2, K_BUCK * PART_B);
    scan_bsum_kernel<<<1, 256, 0, stream>>>(bsum2, K_BUCK);
    scan_apply_kernel<<<K_BUCK, 256, 0, stream>>>(cnt, bsum2, cnt, K_BUCK * PART_B);
    partition_kernel<<<PART_B, 256, 0, stream>>>(src, dst, cnt, P);
    fine_scatter_kernel<<<K_BUCK, 256, 0, stream>>>(P, cnt, deg, rowptr, col);

    const int gx = (N_NODES + 127) / 128;       // 391
    const int gxp = ((gx + 7) / 8) * 8;         // 392
    const int gx64 = (N_NODES + 63) / 64;       // 782
    const int M = N_NODES;

    // ---- L1: G1 (fp32 x, 256->128 raw), agg@128+bias+relu, G2 (128->128 BN) ----
    mfma_gemm2_kernel<8, true, false><<<gxp, 256, 0, stream>>>(
        x, wt[0][0], nullptr, bufA, M, 256, 128, 2, gx, 1,
        nullptr, nullptr, nullptr, nullptr, nullptr, nullptr, nullptr);
    aggregate_bf16_kernel<16, true><<<(N_NODES + 15) / 16, 256, 0, stream>>>(
        bufA, rowptr, col, b[0][0], bufB, N_NODES);
    mfma_gemm2_kernel<8, false, false><<<gxp, 256, 0, stream>>>(
        bufB, wt[0][1], b[0][1], bufC, M, 128, 128, 1, gx, 1,
        bng[0], bnb[0], bnm[0], bnv[0], nullptr, nullptr, nullptr);

    // ---- L2: agg@128, fused MLP (128->256 relu -> 256 BN+relu) ----
    aggregate_bf16_kernel<16, false><<<(N_NODES + 15) / 16, 256, 0, stream>>>(
        bufC, rowptr, col, nullptr, bufA, N_NODES);
    fused_mlp_kernel<128, 256, 256><<<gx64, 256, 0, stream>>>(
        bufA, wt[1][0], wt[1][1],
        0, b[1][0], nullptr, nullptr, nullptr, nullptr,
        1, b[1][1], bng[1], bnb[1], bnm[1], bnv[1],
        bufC, M);

    // ---- L3: G1 (256->128 raw), agg@128+bias+relu ----
    mfma_gemm2_kernel<8, false, false><<<gxp, 256, 0, stream>>>(
        bufC, wt[2][0], nullptr, bufA, M, 256, 128, 2, gx, 1,
        nullptr, nullptr, nullptr, nullptr, nullptr, nullptr, nullptr);
    aggregate_bf16_kernel<16, true><<<(N_NODES + 15) / 16, 256, 0, stream>>>(
        bufA, rowptr, col, b[2][0], bufB, N_NODES);

    // ---- fused: L3 G2 (128->128 BN+relu) -> L4 G1 (128->64 raw) ----
    fused_mlp_kernel<128, 128, 64><<<gx64, 256, 0, stream>>>(
        bufB, wt[2][1], wt[3][0],
        1, b[2][1], bng[2], bnb[2], bnm[2], bnv[2],
        2, nullptr, nullptr, nullptr, nullptr, nullptr,
        bufA, M);

    // ---- L4: agg@64+bias+relu, G2+classifier ----
    aggregate_bf16_kernel<8, true><<<(N_NODES + 31) / 32, 256, 0, stream>>>(
        bufA, rowptr, col, b[3][0], bufB, N_NODES);
    mfma_gemm2_kernel<4, false, true><<<gxp, 256, 0, stream>>>(
        bufB, wt[3][1], b[3][1], nullptr, M, 64, 64, 1, gx, 1,
        bng[3], bnb[3], bnm[3], bnv[3], wc, bc, out);
}